// Round 9
// baseline (785.951 us; speedup 1.0000x reference)
//
#include <hip/hip_runtime.h>
#include <math.h>

typedef __attribute__((ext_vector_type(8))) short short8;
typedef __attribute__((ext_vector_type(4))) short shortx4;
typedef __attribute__((ext_vector_type(4))) float floatx4;

#define BQ 256
#define SQ 256
#define DQ 256
#define HQ 4

__device__ __forceinline__ short f2bf(float f) {
  union { float f; unsigned u; } c; c.f = f;
  unsigned r = c.u + 0x7fffu + ((c.u >> 16) & 1u);
  return (short)(r >> 16);
}
__device__ __forceinline__ float bf2f(short s) {
  union { unsigned u; float f; } c; c.u = ((unsigned)(unsigned short)s) << 16;
  return c.f;
}
__device__ __forceinline__ float gelu_fast(float x) {
  float t = x * (0.7978845608f + 0.0356774081f * x * x);
  return x / (1.0f + __expf(-2.0f * t));
}
__device__ __forceinline__ void async16(const void* g, void* l) {
  __builtin_amdgcn_global_load_lds(
      (const __attribute__((address_space(1))) void*)g,
      (__attribute__((address_space(3))) void*)l, 16, 0, 0);
}

// ---- unified weight transpose+convert (f32 [K,N] -> bf16 [N,K]) + bias concat ------
__global__ __launch_bounds__(256) void wtrans_kernel(
    const float* __restrict__ Wq, const float* __restrict__ Wk, const float* __restrict__ Wv,
    const float* __restrict__ Wo, const float* __restrict__ W1, const float* __restrict__ W2,
    const float* __restrict__ bq, const float* __restrict__ bk, const float* __restrict__ bv,
    short* __restrict__ WqkvT, short* __restrict__ WoT, short* __restrict__ W1T,
    short* __restrict__ W2T, float* __restrict__ bqkv) {
  const int bid = blockIdx.x, tid = threadIdx.x;
  if (bid >= 384) {                       // bias concat: 6 blocks
    int i = bid - 384;                    // l*3+which
    int l = i / 3, which = i - l * 3;
    const float* src = (which == 0) ? bq : ((which == 1) ? bk : bv);
    bqkv[l * 768 + which * 256 + tid] = src[l * 256 + tid];
    return;
  }
  __shared__ float t[64][65];
  const float* src; short* dst; int K, N, tile;
  if (bid < 96)       { int l = bid / 48, r = bid % 48, which = r / 16; tile = r % 16;
    src = ((which == 0) ? Wq : (which == 1) ? Wk : Wv) + l * 65536;
    dst = WqkvT + (l * 3 + which) * 65536; K = 256; N = 256; }
  else if (bid < 128) { int i = bid - 96, l = i / 16; tile = i % 16;
    src = Wo + l * 65536; dst = WoT + l * 65536; K = 256; N = 256; }
  else if (bid < 256) { int i = bid - 128, l = i / 64; tile = i % 64;
    src = W1 + l * 262144; dst = W1T + l * 262144; K = 256; N = 1024; }
  else                { int i = bid - 256, l = i / 64; tile = i % 64;
    src = W2 + l * 262144; dst = W2T + l * 262144; K = 1024; N = 256; }
  const int ntj = N >> 6;
  const int ti = tile / ntj, tj = tile - ti * ntj;
  {
    int r = tid >> 2, c0 = (tid & 3) * 16;
    const float* sp = src + (size_t)(ti * 64 + r) * N + tj * 64 + c0;
#pragma unroll
    for (int j = 0; j < 4; ++j) {
      floatx4 v = *(const floatx4*)(sp + j * 4);
      t[r][c0 + j * 4 + 0] = v[0]; t[r][c0 + j * 4 + 1] = v[1];
      t[r][c0 + j * 4 + 2] = v[2]; t[r][c0 + j * 4 + 3] = v[3];
    }
  }
  __syncthreads();
  {
    int d = tid & 63, ch = tid >> 6;
    short8 o[2];
#pragma unroll
    for (int j = 0; j < 16; ++j) o[j >> 3][j & 7] = f2bf(t[ch * 16 + j][d]);
    short* dp = dst + (size_t)(tj * 64 + d) * K + ti * 64 + ch * 16;
    *(short8*)dp = o[0];
    *(short8*)(dp + 8) = o[1];
  }
}

// ---------------- embedding + LN; writes xb (bf16) and total (f32) ------------------
__global__ __launch_bounds__(256) void embed_kernel(const int* __restrict__ ids,
    const float* __restrict__ item, const float* __restrict__ pos,
    short* __restrict__ xb, float* __restrict__ tot) {
  const int tid = threadIdx.x, lane = tid & 63, w = tid >> 6;
  const int row = blockIdx.x * 4 + w;
  const int s = row & (SQ - 1);
  const int id = ids[row];
  floatx4 a = *(const floatx4*)(item + (size_t)id * DQ + lane * 4);
  floatx4 p = *(const floatx4*)(pos + (size_t)s * DQ + lane * 4);
  float v[4];
#pragma unroll
  for (int i = 0; i < 4; ++i) v[i] = a[i] + p[i];
  float sm = v[0] + v[1] + v[2] + v[3];
  float ss = v[0]*v[0] + v[1]*v[1] + v[2]*v[2] + v[3]*v[3];
#pragma unroll
  for (int off = 32; off; off >>= 1) { sm += __shfl_xor(sm, off); ss += __shfl_xor(ss, off); }
  float mu = sm * (1.0f / DQ);
  float var = ss * (1.0f / DQ) - mu * mu;
  float rs = rsqrtf(var + 1e-5f);
  shortx4 o; floatx4 y;
#pragma unroll
  for (int i = 0; i < 4; ++i) { y[i] = (v[i] - mu) * rs; o[i] = f2bf(y[i]); }
  *(shortx4*)(xb + (size_t)row * DQ + lane * 4) = o;
  *(floatx4*)(tot + (size_t)row * DQ + lane * 4) = y;
}

// ------------- bf16 MFMA GEMM, tile 128x128, 256 threads, 4 waves (2x2) -------------
// (R6-proven: +22 us vs 128x256 for the LN-free GEMMs)
template <int ACT, int SMODE>
__global__ __launch_bounds__(256, 4) void gemm128_kernel(
    const short* __restrict__ A, const short* __restrict__ Bt,
    const float* __restrict__ bias, short* __restrict__ out, short* __restrict__ vt,
    int M, int N, int K) {
  __shared__ short smem[16384];   // 2 x (As 4096 | Bs 4096) shorts = 32768 B
  const int tid = threadIdx.x, lane = tid & 63, w = tid >> 6;   // w in 0..3
  const int lane15 = lane & 15, quad = lane >> 4;
  const int wm = w & 1, wn = w >> 1;

  const int gx = gridDim.x;
  const int nwg = gx * gridDim.y;
  const int orig = blockIdx.y * gx + blockIdx.x;
  const int chunk = nwg >> 3;
  const int sw = (orig & 7) * chunk + (orig >> 3);
  const int bm = sw / gx, bn = sw - bm * gx;

  const int rA = lane >> 2;
  const int swzA = (rA & 3) ^ ((rA >> 2) & 3);
  const int gA = ((lane & 3) ^ swzA) * 8;
  const short* Ag  = A  + (size_t)(bm * 128 + w * 16 + rA) * K + gA;
  const short* Ag2 = Ag + (size_t)64 * K;
  const short* Bg0 = Bt + (size_t)(bn * 128 + w * 16 + rA) * K + gA;
  const short* Bg1 = Bg0 + (size_t)64 * K;
  const int qs = ((quad ^ ((lane15 & 3) ^ ((lane15 >> 2) & 3))) * 8);

  floatx4 acc[4][4] = {};
  const int nk = K >> 5;
#define GSTG2(kb_)                                                       \
  do {                                                                   \
    short* S = smem + (((kb_) & 1) * 8192);                              \
    async16(Ag  + (kb_) * 32, &S[w * 512]);                              \
    async16(Ag2 + (kb_) * 32, &S[2048 + w * 512]);                       \
    async16(Bg0 + (kb_) * 32, &S[4096 + w * 512]);                       \
    async16(Bg1 + (kb_) * 32, &S[6144 + w * 512]);                       \
  } while (0)

  GSTG2(0);
  for (int kb = 0; kb < nk; ++kb) {
    __syncthreads();                       // tile kb resident
    if (kb + 1 < nk) GSTG2(kb + 1);        // prefetch overlaps compute
    const short* Asb = smem + ((kb & 1) * 8192);
    const short* Bsb = Asb + 4096;
    short8 af[4], bfr[4];
#pragma unroll
    for (int i = 0; i < 4; ++i) {
      af[i]  = *(const short8*)&Asb[(wm * 64 + i * 16 + lane15) * 32 + qs];
      bfr[i] = *(const short8*)&Bsb[(wn * 64 + i * 16 + lane15) * 32 + qs];
    }
#pragma unroll
    for (int i = 0; i < 4; ++i)
#pragma unroll
      for (int j = 0; j < 4; ++j)
        acc[i][j] = __builtin_amdgcn_mfma_f32_16x16x32_bf16(bfr[j], af[i], acc[i][j], 0, 0, 0);
  }
#undef GSTG2

  // bias (+ gelu) pre-pass
#pragma unroll
  for (int i = 0; i < 4; ++i)
#pragma unroll
    for (int j = 0; j < 4; ++j) {
      int nloc = wn * 64 + j * 16 + quad * 4;
      floatx4 b4 = *(const floatx4*)(bias + bn * 128 + nloc);
#pragma unroll
      for (int r = 0; r < 4; ++r) {
        float z = acc[i][j][r] + b4[r];
        if (ACT) z = gelu_fast(z);
        acc[i][j][r] = z;
      }
    }

  // epilogue: stage 32x128 sub-tile per i in LDS (stride 132), then coalesced out
#pragma unroll
  for (int i = 0; i < 4; ++i) {
    __syncthreads();
    int lr = wm * 16 + lane15;             // 0..31
#pragma unroll
    for (int j = 0; j < 4; ++j) {
      shortx4 o;
#pragma unroll
      for (int r = 0; r < 4; ++r) o[r] = f2bf(acc[i][j][r]);
      *(shortx4*)&smem[lr * 132 + wn * 64 + j * 16 + quad * 4] = o;
    }
    __syncthreads();
    if (SMODE == 1 && bn >= 4) {           // V -> vt transpose path
      int d = tid & 127, grp = tid >> 7;
      short vv[16];
#pragma unroll
      for (int rr = 0; rr < 16; ++rr) vv[rr] = smem[(grp * 16 + rr) * 132 + d];
      size_t row = ((size_t)((bm >> 1) * 256 + (bn - 4) * 128 + d)) * 256 +
                   (bm & 1) * 128 + grp * 64 + i * 16;
      *(short8*)(vt + row) = *(short8*)&vv[0];
      *(short8*)(vt + row + 8) = *(short8*)&vv[8];
    } else {
#pragma unroll
      for (int it = 0; it < 2; ++it) {
        int t2 = tid + it * 256;
        int lr2 = t2 >> 4, c = (t2 & 15) * 8;
        short8 v = *(const short8*)&smem[lr2 * 132 + c];
        size_t rowg = (size_t)bm * 128 + (lr2 >> 4) * 64 + i * 16 + (lr2 & 15);
        short* dst = (SMODE == 1)
            ? out + (size_t)(bn >> 1) * M * 256 + rowg * 256 + (bn & 1) * 128 + c
            : out + rowg * (size_t)N + bn * 128 + c;
        *(short8*)dst = v;
      }
    }
  }
}

// ------- bf16 MFMA GEMM + row LayerNorm, tile 64x256, 256 threads, 4 waves ----------
// Wave w owns cols w*64..w*64+63 (acc[4][4], identical per-wave structure to the
// proven kernels; pure re-indexing wm->0, wn->w). LDS = 2x(A 4KB + B 16KB) = 40960 B
// exactly -> 4 blocks/CU; grid M/64 = 1024 = 4*256 single full round (R7's shape).
// Cross-wave LN reduce via redS overlaying A0 (nk even for both uses). RES: +bf16
// residual before LN (Wo). TOT: f32 tot RMW after LN (W2). N = 256 fixed.
template <int RES, int TOT>
__global__ __launch_bounds__(256, 4) void ln64_kernel(
    const short* __restrict__ A, const short* __restrict__ Bt,
    const float* __restrict__ bias, const short* __restrict__ res,
    short* __restrict__ out, float* __restrict__ tot, int M, int K) {
  __shared__ short smem[20480];   // [A0 2048 | B0 8192 | A1 2048 | B1 8192] shorts
  float* redS  = (float*)smem;    // overlays A0 after the K-loop (nk even)
  float* redS2 = redS + 256;
  const int tid = threadIdx.x, lane = tid & 63, w = tid >> 6;   // w in 0..3
  const int lane15 = lane & 15, quad = lane >> 4;

  // XCD-chunked bijective swizzle over gridDim.y (1024, multiple of 8)
  const int nwg = gridDim.y;
  const int orig = blockIdx.y;
  const int chunk = nwg >> 3;
  const int bm = (orig & 7) * chunk + (orig >> 3);

  const int rA = lane >> 2;
  const int swzA = (rA & 3) ^ ((rA >> 2) & 3);
  const int gA = ((lane & 3) ^ swzA) * 8;
  const short* Ag  = A  + (size_t)(bm * 64 + w * 16 + rA) * K + gA;
  const short* Bg0 = Bt + (size_t)(w * 16 + rA) * K + gA;       // rows 0..63   (+c*64*K)
  const short* Bg1 = Bg0 + (size_t)64 * K;
  const short* Bg2 = Bg0 + (size_t)128 * K;
  const short* Bg3 = Bg0 + (size_t)192 * K;
  const int qs = ((quad ^ ((lane15 & 3) ^ ((lane15 >> 2) & 3))) * 8);

  floatx4 acc[4][4] = {};
  const int nk = K >> 5;
#define LSTG(kb_)                                                        \
  do {                                                                   \
    short* S = smem + (((kb_) & 1) * 10240);                             \
    async16(Ag  + (kb_) * 32, &S[w * 512]);                              \
    async16(Bg0 + (kb_) * 32, &S[2048 + w * 512]);                       \
    async16(Bg1 + (kb_) * 32, &S[4096 + w * 512]);                       \
    async16(Bg2 + (kb_) * 32, &S[6144 + w * 512]);                       \
    async16(Bg3 + (kb_) * 32, &S[8192 + w * 512]);                       \
  } while (0)

  LSTG(0);
  for (int kb = 0; kb < nk; ++kb) {
    __syncthreads();                       // tile kb resident
    if (kb + 1 < nk) LSTG(kb + 1);         // prefetch overlaps compute
    const short* Asb = smem + ((kb & 1) * 10240);
    const short* Bsb = Asb + 2048;
    short8 af[4], bfr[4];
#pragma unroll
    for (int i = 0; i < 4; ++i) {
      af[i]  = *(const short8*)&Asb[(i * 16 + lane15) * 32 + qs];
      bfr[i] = *(const short8*)&Bsb[(w * 64 + i * 16 + lane15) * 32 + qs];
    }
#pragma unroll
    for (int i = 0; i < 4; ++i)
#pragma unroll
      for (int j = 0; j < 4; ++j)
        acc[i][j] = __builtin_amdgcn_mfma_f32_16x16x32_bf16(bfr[j], af[i], acc[i][j], 0, 0, 0);
  }
#undef LSTG

  // bias (+ residual) and per-row partial sums
  float sum_[4], sq_[4];
#pragma unroll
  for (int i = 0; i < 4; ++i) { sum_[i] = 0.0f; sq_[i] = 0.0f; }
#pragma unroll
  for (int i = 0; i < 4; ++i) {
    size_t rowg = (size_t)bm * 64 + i * 16 + lane15;
#pragma unroll
    for (int j = 0; j < 4; ++j) {
      int nloc = w * 64 + j * 16 + quad * 4;
      floatx4 b4 = *(const floatx4*)(bias + nloc);
      shortx4 r4;
      if (RES) r4 = *(const shortx4*)(res + rowg * 256 + nloc);
#pragma unroll
      for (int r = 0; r < 4; ++r) {
        float z = acc[i][j][r] + b4[r];
        if (RES) z += bf2f(r4[r]);
        acc[i][j][r] = z;
        sum_[i] += z; sq_[i] += z * z;
      }
    }
  }

  // reduce within wave (cols), then across the 4 waves via LDS
#pragma unroll
  for (int i = 0; i < 4; ++i) {
    sum_[i] += __shfl_xor(sum_[i], 16); sum_[i] += __shfl_xor(sum_[i], 32);
    sq_[i]  += __shfl_xor(sq_[i], 16);  sq_[i]  += __shfl_xor(sq_[i], 32);
  }
  if (quad == 0) {
#pragma unroll
    for (int i = 0; i < 4; ++i) {
      int lr = i * 16 + lane15;
      redS[lr * 4 + w] = sum_[i];
      redS2[lr * 4 + w] = sq_[i];
    }
  }
  __syncthreads();
#pragma unroll
  for (int i = 0; i < 4; ++i) {
    int lr = i * 16 + lane15;
    float s = redS[lr * 4] + redS[lr * 4 + 1] + redS[lr * 4 + 2] + redS[lr * 4 + 3];
    float q = redS2[lr * 4] + redS2[lr * 4 + 1] + redS2[lr * 4 + 2] + redS2[lr * 4 + 3];
    float mu = s * (1.0f / 256.0f);
    float var = q * (1.0f / 256.0f) - mu * mu;
    float rs = rsqrtf(var + 1e-5f);
    size_t rowg = (size_t)bm * 64 + i * 16 + lane15;
#pragma unroll
    for (int j = 0; j < 4; ++j) {
      int nloc = w * 64 + j * 16 + quad * 4;
      floatx4 y;
#pragma unroll
      for (int r = 0; r < 4; ++r) y[r] = (acc[i][j][r] - mu) * rs;
      acc[i][j] = y;
      if (TOT) {
        floatx4* tp = (floatx4*)(tot + rowg * 256 + nloc);
        floatx4 t = *tp;
#pragma unroll
        for (int r = 0; r < 4; ++r) t[r] += y[r];
        *tp = t;
      }
    }
  }

  // epilogue: per i stage 16x256 bf16 (stride 264) then 128-B line writes
#pragma unroll
  for (int i = 0; i < 4; ++i) {
    __syncthreads();
#pragma unroll
    for (int j = 0; j < 4; ++j) {
      shortx4 o;
#pragma unroll
      for (int r = 0; r < 4; ++r) o[r] = f2bf(acc[i][j][r]);
      *(shortx4*)&smem[lane15 * 264 + w * 64 + j * 16 + quad * 4] = o;
    }
    __syncthreads();
#pragma unroll
    for (int it = 0; it < 2; ++it) {
      int t2 = tid + it * 256;
      int lr2 = t2 >> 5, c = (t2 & 31) * 8;
      short8 v = *(const short8*)&smem[lr2 * 264 + c];
      size_t rowg = (size_t)bm * 64 + i * 16 + lr2;
      *(short8*)(out + rowg * 256 + c) = v;
    }
  }
}

// ---------------- flash attention: block = (b, h), 512 threads, 8 waves -------------
// (R7-proven: ballot pad mask + half-width P, LDS 40960 -> 4 blocks/CU, 89 us)
__global__ __launch_bounds__(512, 4) void attn_kernel(
    const short* __restrict__ qg, const short* __restrict__ kg,
    const short* __restrict__ vtg, const int* __restrict__ ids,
    short* __restrict__ ctxg) {
  __shared__ short lds[20480];   // K[2][64][64] | V[2][64][64]@8192 | P[8][16][32]@16384
  const int tid = threadIdx.x, lane = tid & 63, w = tid >> 6;
  const int lane15 = lane & 15, quad = lane >> 4, l7 = lane15 & 7;
  const int h = blockIdx.x & 3, b = blockIdx.x >> 2;

  const int stA[2] = {w, 15 - w};
  short8 qf[2][2];
#pragma unroll
  for (int tt = 0; tt < 2; ++tt) {
    int q0 = stA[tt] * 16;
#pragma unroll
    for (int ks = 0; ks < 2; ++ks)
      qf[tt][ks] = *(const short8*)(qg + (size_t)(b * 256 + q0 + lane15) * 256 +
                                    h * 64 + ks * 32 + quad * 8);
  }

  float m_[2][4], l_[2][4];
  floatx4 o[2][4];
#pragma unroll
  for (int tt = 0; tt < 2; ++tt)
#pragma unroll
    for (int r = 0; r < 4; ++r) {
      m_[tt][r] = -1e30f; l_[tt][r] = 0.0f;
#pragma unroll
      for (int dt = 0; dt < 4; ++dt) o[tt][dt][r] = 0.0f;
    }

  // staging: thread covers row tid>>3 (0..63), 16B group (tid&7)^(row&7)
  const int srow = tid >> 3;
  const int g8 = ((tid & 7) ^ (srow & 7)) * 8;
  const short* kgp = kg + (size_t)(b * 256 + srow) * 256 + h * 64 + g8;   // + kb*64*256
  const short* vgp = vtg + (size_t)(b * 256 + h * 64 + srow) * 256 + g8;  // + kb*64
  short* pbuf = &lds[16384 + w * 512];

#define STG(kb_, ib_)                                                     \
  do {                                                                    \
    async16(kgp + (size_t)(kb_) * 64 * 256, &lds[(ib_) * 4096 + w * 512]);\
    async16(vgp + (kb_) * 64, &lds[8192 + (ib_) * 4096 + w * 512]);       \
  } while (0)

  STG(0, 0);

  for (int kb = 0; kb < 4; ++kb) {
    __syncthreads();
    if (kb < 3) STG(kb + 1, (kb + 1) & 1);
    const short* kbuf = &lds[(kb & 1) * 4096];
    const short* vbuf = &lds[8192 + (kb & 1) * 4096];
    // padding mask for this 64-key tile: bit l = (ids[b,kb*64+l] > 0)
    const unsigned long long pm = __ballot(ids[b * 256 + kb * 64 + lane] > 0);

#pragma unroll
    for (int tt = 0; tt < 2; ++tt) {
      const int st = stA[tt];
      if (st < 4 * kb) continue;                 // causally done
      const int q0 = st * 16;
      const int diag = (st >> 2) == kb;
      const int stlo = st & 3;
      floatx4 e[4];
#pragma unroll
      for (int t16 = 0; t16 < 4; ++t16) {
        if (diag && t16 > stlo) {                // fully masked sub-block
          e[t16] = (floatx4){-1e30f, -1e30f, -1e30f, -1e30f};
          continue;
        }
        floatx4 a = {0.f, 0.f, 0.f, 0.f};
#pragma unroll
        for (int ks = 0; ks < 2; ++ks) {
          short8 kf = *(const short8*)&kbuf[(t16 * 16 + lane15) * 64 +
                                            (((ks * 4 + quad) ^ l7) * 8)];
          a = __builtin_amdgcn_mfma_f32_16x16x32_bf16(qf[tt][ks], kf, a, 0, 0, 0);
        }
        float pb = ((pm >> (t16 * 16 + lane15)) & 1ull) ? 0.0f : -10000.0f;
        if (diag && t16 == stlo) {
          int kk = kb * 64 + t16 * 16 + lane15;
#pragma unroll
          for (int r = 0; r < 4; ++r)
            e[t16][r] = a[r] * 0.125f + ((kk <= q0 + quad * 4 + r) ? pb : -10000.0f);
        } else {
#pragma unroll
          for (int r = 0; r < 4; ++r) e[t16][r] = a[r] * 0.125f + pb;
        }
      }
      // online softmax over this 64-key tile; pack P rows to bf16 pairs
      unsigned pk01[4], pk23[4];
#pragma unroll
      for (int r = 0; r < 4; ++r) {
        float mx = fmaxf(fmaxf(e[0][r], e[1][r]), fmaxf(e[2][r], e[3][r]));
        mx = fmaxf(mx, __shfl_xor(mx, 1)); mx = fmaxf(mx, __shfl_xor(mx, 2));
        mx = fmaxf(mx, __shfl_xor(mx, 4)); mx = fmaxf(mx, __shfl_xor(mx, 8));
        float mn = fmaxf(m_[tt][r], mx);
        float alpha = __expf(m_[tt][r] - mn);
        m_[tt][r] = mn;
        float s = 0.0f;
#pragma unroll
        for (int t16 = 0; t16 < 4; ++t16) {
          float ev = __expf(e[t16][r] - mn);
          e[t16][r] = ev; s += ev;
        }
        s += __shfl_xor(s, 1); s += __shfl_xor(s, 2);
        s += __shfl_xor(s, 4); s += __shfl_xor(s, 8);
        l_[tt][r] = l_[tt][r] * alpha + s;
#pragma unroll
        for (int dt = 0; dt < 4; ++dt) o[tt][dt][r] *= alpha;
        pk01[r] = ((unsigned)(unsigned short)f2bf(e[0][r])) |
                  (((unsigned)(unsigned short)f2bf(e[1][r])) << 16);
        pk23[r] = ((unsigned)(unsigned short)f2bf(e[2][r])) |
                  (((unsigned)(unsigned short)f2bf(e[3][r])) << 16);
      }
      // PV in two 32-key passes through the half-width per-wave P buffer
#pragma unroll
      for (int kh = 0; kh < 2; ++kh) {
#pragma unroll
        for (int r = 0; r < 4; ++r) {
          int qloc = quad * 4 + r;
          unsigned pk = kh ? pk23[r] : pk01[r];
#pragma unroll
          for (int th = 0; th < 2; ++th) {
            int c = ((th * 2 + (lane15 >> 3)) ^ quad) & 3;
            pbuf[qloc * 32 + c * 8 + l7] = (short)(pk >> (th * 16));
          }
        }
        short8 pf = *(const short8*)&pbuf[lane15 * 32 +
                                          (((quad ^ (lane15 >> 2)) & 3) * 8)];
#pragma unroll
        for (int dt = 0; dt < 4; ++dt) {
          short8 vf = *(const short8*)&vbuf[(dt * 16 + lane15) * 64 +
                        (((kh * 4 + quad) ^ l7) * 8)];
          o[tt][dt] = __builtin_amdgcn_mfma_f32_16x16x32_bf16(pf, vf, o[tt][dt], 0, 0, 0);
        }
      }
    }
  }

  // epilogue: per wave, two passes of 16x32 through pbuf, then 16B/lane reads and
  // 64B-contiguous global stores per row.
#pragma unroll
  for (int tt = 0; tt < 2; ++tt) {
    const int q0 = stA[tt] * 16;
    float inv_[4];
#pragma unroll
    for (int r = 0; r < 4; ++r) inv_[r] = 1.0f / l_[tt][r];
#pragma unroll
    for (int p = 0; p < 2; ++p) {
#pragma unroll
      for (int r = 0; r < 4; ++r) {
        int qloc = quad * 4 + r;
#pragma unroll
        for (int dh = 0; dh < 2; ++dh) {
          int c = ((dh * 2 + (lane15 >> 3)) ^ quad) & 3;
          pbuf[qloc * 32 + c * 8 + l7] = f2bf(o[tt][p * 2 + dh][r] * inv_[r]);
        }
      }
      int row = lane >> 2, u = lane & 3;
      int lc = u ^ ((row >> 2) & 3);
      short8 v = *(const short8*)&pbuf[row * 32 + u * 8];
      *(short8*)(ctxg + (size_t)(b * 256 + q0 + row) * 256 + h * 64 + p * 32 + lc * 8) = v;
    }
  }
}

extern "C" void kernel_launch(void* const* d_in, const int* in_sizes, int n_in,
                              void* d_out, int out_size, void* d_ws, size_t ws_size,
                              hipStream_t stream) {
  const int*   ids  = (const int*)d_in[0];
  const float* item = (const float*)d_in[1];
  const float* pos  = (const float*)d_in[2];
  const float* Wq = (const float*)d_in[3];  const float* bq = (const float*)d_in[4];
  const float* Wk = (const float*)d_in[5];  const float* bk = (const float*)d_in[6];
  const float* Wv = (const float*)d_in[7];  const float* bv = (const float*)d_in[8];
  const float* Wo = (const float*)d_in[9];  const float* bo = (const float*)d_in[10];
  const float* W1 = (const float*)d_in[11]; const float* b1 = (const float*)d_in[12];
  const float* W2 = (const float*)d_in[13]; const float* b2 = (const float*)d_in[14];
  float* out = (float*)d_out;

  const size_t EL = (size_t)BQ * SQ * DQ;   // 16,777,216
  short* qb    = (short*)d_ws;
  short* kb_   = qb + EL;
  short* vt    = kb_ + EL;                  // V^T [b][d][s]
  short* ctxb  = vt + EL;
  short* gb    = qb;                        // [M,1024] spans qb..ctxb (dead at W1)
  short* xb    = ctxb + EL;
  short* hb    = xb + EL;
  short* WqkvT = hb + EL;                   // [L][3][256][256]
  short* WoT   = WqkvT + 2 * 3 * 65536;
  short* W1T   = WoT + 2 * 65536;           // [L][1024][256]
  short* W2T   = W1T + 2 * 262144;          // [L][256][1024]
  float* bqkv  = (float*)(W2T + 2 * 262144);

  const int M = BQ * SQ;                    // 65536

  wtrans_kernel<<<390, 256, 0, stream>>>(Wq, Wk, Wv, Wo, W1, W2, bq, bk, bv,
                                         WqkvT, WoT, W1T, W2T, bqkv);
  embed_kernel<<<M / 4, 256, 0, stream>>>(ids, item, pos, xb, out);

  for (int l = 0; l < 2; ++l) {
    gemm128_kernel<0, 1><<<dim3(6, M / 128), 256, 0, stream>>>(
        xb, WqkvT + (size_t)l * 3 * 65536, bqkv + l * 768, qb, vt, M, 768, 256);
    attn_kernel<<<BQ * HQ, 512, 0, stream>>>(qb, kb_, vt, ids, ctxb);
    ln64_kernel<1, 0><<<dim3(1, M / 64), 256, 0, stream>>>(
        ctxb, WoT + (size_t)l * 65536, bo + l * 256, xb, hb, nullptr, M, 256);
    gemm128_kernel<1, 0><<<dim3(8, M / 128), 256, 0, stream>>>(
        hb, W1T + (size_t)l * 262144, b1 + l * 1024, gb, nullptr, M, 1024, 256);
    ln64_kernel<0, 1><<<dim3(1, M / 64), 256, 0, stream>>>(
        gb, W2T + (size_t)l * 262144, b2 + l * 256, nullptr, xb, out, M, 1024);
  }
}

// Round 10
// 746.868 us; speedup vs baseline: 1.0523x; 1.0523x over previous
//
#include <hip/hip_runtime.h>
#include <math.h>

typedef __attribute__((ext_vector_type(8))) short short8;
typedef __attribute__((ext_vector_type(4))) short shortx4;
typedef __attribute__((ext_vector_type(4))) float floatx4;

#define BQ 256
#define SQ 256
#define DQ 256
#define HQ 4

__device__ __forceinline__ short f2bf(float f) {
  union { float f; unsigned u; } c; c.f = f;
  unsigned r = c.u + 0x7fffu + ((c.u >> 16) & 1u);
  return (short)(r >> 16);
}
__device__ __forceinline__ float bf2f(short s) {
  union { unsigned u; float f; } c; c.u = ((unsigned)(unsigned short)s) << 16;
  return c.f;
}
__device__ __forceinline__ float gelu_fast(float x) {
  float t = x * (0.7978845608f + 0.0356774081f * x * x);
  return x / (1.0f + __expf(-2.0f * t));
}
__device__ __forceinline__ void async16(const void* g, void* l) {
  __builtin_amdgcn_global_load_lds(
      (const __attribute__((address_space(1))) void*)g,
      (__attribute__((address_space(3))) void*)l, 16, 0, 0);
}

// ---- unified weight transpose+convert (f32 [K,N] -> bf16 [N,K]) + bias concat ------
__global__ __launch_bounds__(256) void wtrans_kernel(
    const float* __restrict__ Wq, const float* __restrict__ Wk, const float* __restrict__ Wv,
    const float* __restrict__ Wo, const float* __restrict__ W1, const float* __restrict__ W2,
    const float* __restrict__ bq, const float* __restrict__ bk, const float* __restrict__ bv,
    short* __restrict__ WqkvT, short* __restrict__ WoT, short* __restrict__ W1T,
    short* __restrict__ W2T, float* __restrict__ bqkv) {
  const int bid = blockIdx.x, tid = threadIdx.x;
  if (bid >= 384) {                       // bias concat: 6 blocks
    int i = bid - 384;                    // l*3+which
    int l = i / 3, which = i - l * 3;
    const float* src = (which == 0) ? bq : ((which == 1) ? bk : bv);
    bqkv[l * 768 + which * 256 + tid] = src[l * 256 + tid];
    return;
  }
  __shared__ float t[64][65];
  const float* src; short* dst; int K, N, tile;
  if (bid < 96)       { int l = bid / 48, r = bid % 48, which = r / 16; tile = r % 16;
    src = ((which == 0) ? Wq : (which == 1) ? Wk : Wv) + l * 65536;
    dst = WqkvT + (l * 3 + which) * 65536; K = 256; N = 256; }
  else if (bid < 128) { int i = bid - 96, l = i / 16; tile = i % 16;
    src = Wo + l * 65536; dst = WoT + l * 65536; K = 256; N = 256; }
  else if (bid < 256) { int i = bid - 128, l = i / 64; tile = i % 64;
    src = W1 + l * 262144; dst = W1T + l * 262144; K = 256; N = 1024; }
  else                { int i = bid - 256, l = i / 64; tile = i % 64;
    src = W2 + l * 262144; dst = W2T + l * 262144; K = 1024; N = 256; }
  const int ntj = N >> 6;
  const int ti = tile / ntj, tj = tile - ti * ntj;
  {
    int r = tid >> 2, c0 = (tid & 3) * 16;
    const float* sp = src + (size_t)(ti * 64 + r) * N + tj * 64 + c0;
#pragma unroll
    for (int j = 0; j < 4; ++j) {
      floatx4 v = *(const floatx4*)(sp + j * 4);
      t[r][c0 + j * 4 + 0] = v[0]; t[r][c0 + j * 4 + 1] = v[1];
      t[r][c0 + j * 4 + 2] = v[2]; t[r][c0 + j * 4 + 3] = v[3];
    }
  }
  __syncthreads();
  {
    int d = tid & 63, ch = tid >> 6;
    short8 o[2];
#pragma unroll
    for (int j = 0; j < 16; ++j) o[j >> 3][j & 7] = f2bf(t[ch * 16 + j][d]);
    short* dp = dst + (size_t)(tj * 64 + d) * K + ti * 64 + ch * 16;
    *(short8*)dp = o[0];
    *(short8*)(dp + 8) = o[1];
  }
}

// ---------------- embedding + LN; writes xb (bf16) and total (f32) ------------------
__global__ __launch_bounds__(256) void embed_kernel(const int* __restrict__ ids,
    const float* __restrict__ item, const float* __restrict__ pos,
    short* __restrict__ xb, float* __restrict__ tot) {
  const int tid = threadIdx.x, lane = tid & 63, w = tid >> 6;
  const int row = blockIdx.x * 4 + w;
  const int s = row & (SQ - 1);
  const int id = ids[row];
  floatx4 a = *(const floatx4*)(item + (size_t)id * DQ + lane * 4);
  floatx4 p = *(const floatx4*)(pos + (size_t)s * DQ + lane * 4);
  float v[4];
#pragma unroll
  for (int i = 0; i < 4; ++i) v[i] = a[i] + p[i];
  float sm = v[0] + v[1] + v[2] + v[3];
  float ss = v[0]*v[0] + v[1]*v[1] + v[2]*v[2] + v[3]*v[3];
#pragma unroll
  for (int off = 32; off; off >>= 1) { sm += __shfl_xor(sm, off); ss += __shfl_xor(ss, off); }
  float mu = sm * (1.0f / DQ);
  float var = ss * (1.0f / DQ) - mu * mu;
  float rs = rsqrtf(var + 1e-5f);
  shortx4 o; floatx4 y;
#pragma unroll
  for (int i = 0; i < 4; ++i) { y[i] = (v[i] - mu) * rs; o[i] = f2bf(y[i]); }
  *(shortx4*)(xb + (size_t)row * DQ + lane * 4) = o;
  *(floatx4*)(tot + (size_t)row * DQ + lane * 4) = y;
}

// ------------- bf16 MFMA GEMM, tile 128x128, 256 threads, 4 waves (2x2) -------------
// (R6-proven: +22 us vs 128x256 for the LN-free GEMMs)
template <int ACT, int SMODE>
__global__ __launch_bounds__(256, 4) void gemm128_kernel(
    const short* __restrict__ A, const short* __restrict__ Bt,
    const float* __restrict__ bias, short* __restrict__ out, short* __restrict__ vt,
    int M, int N, int K) {
  __shared__ short smem[16384];   // 2 x (As 4096 | Bs 4096) shorts = 32768 B
  const int tid = threadIdx.x, lane = tid & 63, w = tid >> 6;   // w in 0..3
  const int lane15 = lane & 15, quad = lane >> 4;
  const int wm = w & 1, wn = w >> 1;

  const int gx = gridDim.x;
  const int nwg = gx * gridDim.y;
  const int orig = blockIdx.y * gx + blockIdx.x;
  const int chunk = nwg >> 3;
  const int sw = (orig & 7) * chunk + (orig >> 3);
  const int bm = sw / gx, bn = sw - bm * gx;

  const int rA = lane >> 2;
  const int swzA = (rA & 3) ^ ((rA >> 2) & 3);
  const int gA = ((lane & 3) ^ swzA) * 8;
  const short* Ag  = A  + (size_t)(bm * 128 + w * 16 + rA) * K + gA;
  const short* Ag2 = Ag + (size_t)64 * K;
  const short* Bg0 = Bt + (size_t)(bn * 128 + w * 16 + rA) * K + gA;
  const short* Bg1 = Bg0 + (size_t)64 * K;
  const int qs = ((quad ^ ((lane15 & 3) ^ ((lane15 >> 2) & 3))) * 8);

  floatx4 acc[4][4] = {};
  const int nk = K >> 5;
#define GSTG2(kb_)                                                       \
  do {                                                                   \
    short* S = smem + (((kb_) & 1) * 8192);                              \
    async16(Ag  + (kb_) * 32, &S[w * 512]);                              \
    async16(Ag2 + (kb_) * 32, &S[2048 + w * 512]);                       \
    async16(Bg0 + (kb_) * 32, &S[4096 + w * 512]);                       \
    async16(Bg1 + (kb_) * 32, &S[6144 + w * 512]);                       \
  } while (0)

  GSTG2(0);
  for (int kb = 0; kb < nk; ++kb) {
    __syncthreads();                       // tile kb resident
    if (kb + 1 < nk) GSTG2(kb + 1);        // prefetch overlaps compute
    const short* Asb = smem + ((kb & 1) * 8192);
    const short* Bsb = Asb + 4096;
    short8 af[4], bfr[4];
#pragma unroll
    for (int i = 0; i < 4; ++i) {
      af[i]  = *(const short8*)&Asb[(wm * 64 + i * 16 + lane15) * 32 + qs];
      bfr[i] = *(const short8*)&Bsb[(wn * 64 + i * 16 + lane15) * 32 + qs];
    }
#pragma unroll
    for (int i = 0; i < 4; ++i)
#pragma unroll
      for (int j = 0; j < 4; ++j)
        acc[i][j] = __builtin_amdgcn_mfma_f32_16x16x32_bf16(bfr[j], af[i], acc[i][j], 0, 0, 0);
  }
#undef GSTG2

  // bias (+ gelu) pre-pass
#pragma unroll
  for (int i = 0; i < 4; ++i)
#pragma unroll
    for (int j = 0; j < 4; ++j) {
      int nloc = wn * 64 + j * 16 + quad * 4;
      floatx4 b4 = *(const floatx4*)(bias + bn * 128 + nloc);
#pragma unroll
      for (int r = 0; r < 4; ++r) {
        float z = acc[i][j][r] + b4[r];
        if (ACT) z = gelu_fast(z);
        acc[i][j][r] = z;
      }
    }

  // epilogue: stage 32x128 sub-tile per i in LDS (stride 132), then coalesced out
#pragma unroll
  for (int i = 0; i < 4; ++i) {
    __syncthreads();
    int lr = wm * 16 + lane15;             // 0..31
#pragma unroll
    for (int j = 0; j < 4; ++j) {
      shortx4 o;
#pragma unroll
      for (int r = 0; r < 4; ++r) o[r] = f2bf(acc[i][j][r]);
      *(shortx4*)&smem[lr * 132 + wn * 64 + j * 16 + quad * 4] = o;
    }
    __syncthreads();
    if (SMODE == 1 && bn >= 4) {           // V -> vt transpose path
      int d = tid & 127, grp = tid >> 7;
      short vv[16];
#pragma unroll
      for (int rr = 0; rr < 16; ++rr) vv[rr] = smem[(grp * 16 + rr) * 132 + d];
      size_t row = ((size_t)((bm >> 1) * 256 + (bn - 4) * 128 + d)) * 256 +
                   (bm & 1) * 128 + grp * 64 + i * 16;
      *(short8*)(vt + row) = *(short8*)&vv[0];
      *(short8*)(vt + row + 8) = *(short8*)&vv[8];
    } else {
#pragma unroll
      for (int it = 0; it < 2; ++it) {
        int t2 = tid + it * 256;
        int lr2 = t2 >> 4, c = (t2 & 15) * 8;
        short8 v = *(const short8*)&smem[lr2 * 132 + c];
        size_t rowg = (size_t)bm * 128 + (lr2 >> 4) * 64 + i * 16 + (lr2 & 15);
        short* dst = (SMODE == 1)
            ? out + (size_t)(bn >> 1) * M * 256 + rowg * 256 + (bn & 1) * 128 + c
            : out + rowg * (size_t)N + bn * 128 + c;
        *(short8*)dst = v;
      }
    }
  }
}

// ---------------- bf16 MFMA GEMM, tile 128x256, 512 threads, swizzled LDS -----------
// Double-buffered K-loop + XCD swizzle. Used for LN GEMMs (Wo: LN+RES, W2: LN+TOT)
// which need BN = 256 for the row-wise LayerNorm. (R9 showed the 64-row LN tile loses
// on B-panel L2 re-reads: B-traffic scales with block count; keep 128-row tiles.)
template <int ACT, int LN, int RES, int TOT, int SMODE>
__global__ __launch_bounds__(512, 4) void gemm_kernel(
    const short* __restrict__ A, const short* __restrict__ Bt,
    const float* __restrict__ bias, const short* __restrict__ res,
    short* __restrict__ out, float* __restrict__ tot, short* __restrict__ vt,
    int M, int N, int K) {
  __shared__ short smem[26624];   // 2 x (As 4096 | Bs 8192) shorts = 49152 B | red @24576 (4 KB)
  float* redS  = (float*)(smem + 24576);
  float* redS2 = redS + 512;
  const int tid = threadIdx.x, lane = tid & 63, w = tid >> 6;
  const int lane15 = lane & 15, quad = lane >> 4;
  const int wm = w & 1, wn = w >> 1;

  const int gx = gridDim.x;
  const int nwg = gx * gridDim.y;
  const int orig = blockIdx.y * gx + blockIdx.x;
  const int chunk = nwg >> 3;
  const int sw = (orig & 7) * chunk + (orig >> 3);
  const int bm = sw / gx, bn = sw - bm * gx;

  const int rA = lane >> 2;
  const int swzA = (rA & 3) ^ ((rA >> 2) & 3);
  const int gA = ((lane & 3) ^ swzA) * 8;
  const short* Ag  = A  + (size_t)(bm * 128 + w * 16 + rA) * K + gA;
  const short* Bg0 = Bt + (size_t)(bn * 256 + w * 32 + rA) * K + gA;
  const short* Bg1 = Bg0 + (size_t)16 * K;
  const int qs = ((quad ^ ((lane15 & 3) ^ ((lane15 >> 2) & 3))) * 8);

  floatx4 acc[4][4] = {};
  const int nk = K >> 5;
#define GSTG(kb_)                                                        \
  do {                                                                   \
    short* As_ = smem + (((kb_) & 1) * 12288);                           \
    async16(Ag  + (kb_) * 32, &As_[w * 512]);                            \
    async16(Bg0 + (kb_) * 32, &As_[4096 + w * 1024]);                    \
    async16(Bg1 + (kb_) * 32, &As_[4096 + w * 1024 + 512]);              \
  } while (0)

  GSTG(0);
  for (int kb = 0; kb < nk; ++kb) {
    __syncthreads();                       // tile kb resident (drains vmcnt)
    if (kb + 1 < nk) GSTG(kb + 1);         // prefetch overlaps compute below
    const short* Asb = smem + ((kb & 1) * 12288);
    const short* Bsb = Asb + 4096;
    short8 af[4], bfr[4];
#pragma unroll
    for (int i = 0; i < 4; ++i) {
      af[i]  = *(const short8*)&Asb[(wm * 64 + i * 16 + lane15) * 32 + qs];
      bfr[i] = *(const short8*)&Bsb[(wn * 64 + i * 16 + lane15) * 32 + qs];
    }
#pragma unroll
    for (int i = 0; i < 4; ++i)
#pragma unroll
      for (int j = 0; j < 4; ++j)
        acc[i][j] = __builtin_amdgcn_mfma_f32_16x16x32_bf16(bfr[j], af[i], acc[i][j], 0, 0, 0);
  }
#undef GSTG

  float sum_[4], sq_[4];
#pragma unroll
  for (int i = 0; i < 4; ++i) { sum_[i] = 0.0f; sq_[i] = 0.0f; }
#pragma unroll
  for (int i = 0; i < 4; ++i) {
    size_t rowg = (size_t)bm * 128 + wm * 64 + i * 16 + lane15;
#pragma unroll
    for (int j = 0; j < 4; ++j) {
      int nloc = wn * 64 + j * 16 + quad * 4;
      floatx4 b4 = *(const floatx4*)(bias + bn * 256 + nloc);
      shortx4 r4;
      if (RES) r4 = *(const shortx4*)(res + rowg * 256 + nloc);
#pragma unroll
      for (int r = 0; r < 4; ++r) {
        float z = acc[i][j][r] + b4[r];
        if (RES) z += bf2f(r4[r]);
        if (ACT) z = gelu_fast(z);
        acc[i][j][r] = z;
        if (LN) { sum_[i] += z; sq_[i] += z * z; }
      }
    }
  }

  if (LN) {
#pragma unroll
    for (int i = 0; i < 4; ++i) {
      sum_[i] += __shfl_xor(sum_[i], 16); sum_[i] += __shfl_xor(sum_[i], 32);
      sq_[i]  += __shfl_xor(sq_[i], 16);  sq_[i]  += __shfl_xor(sq_[i], 32);
    }
    if (quad == 0) {
#pragma unroll
      for (int i = 0; i < 4; ++i) {
        int lr = wm * 64 + i * 16 + lane15;
        redS[lr * 4 + wn] = sum_[i];
        redS2[lr * 4 + wn] = sq_[i];
      }
    }
    __syncthreads();
#pragma unroll
    for (int i = 0; i < 4; ++i) {
      int lr = wm * 64 + i * 16 + lane15;
      float s = redS[lr * 4] + redS[lr * 4 + 1] + redS[lr * 4 + 2] + redS[lr * 4 + 3];
      float q = redS2[lr * 4] + redS2[lr * 4 + 1] + redS2[lr * 4 + 2] + redS2[lr * 4 + 3];
      float mu = s * (1.0f / 256.0f);
      float var = q * (1.0f / 256.0f) - mu * mu;
      float rs = rsqrtf(var + 1e-5f);
      size_t rowg = (size_t)bm * 128 + wm * 64 + i * 16 + lane15;
#pragma unroll
      for (int j = 0; j < 4; ++j) {
        int nloc = wn * 64 + j * 16 + quad * 4;
        floatx4 y;
#pragma unroll
        for (int r = 0; r < 4; ++r) y[r] = (acc[i][j][r] - mu) * rs;
        acc[i][j] = y;
        if (TOT) {
          floatx4* tp = (floatx4*)(tot + rowg * 256 + nloc);
          floatx4 t = *tp;
#pragma unroll
          for (int r = 0; r < 4; ++r) t[r] += y[r];
          *tp = t;
        }
      }
    }
  }

#pragma unroll
  for (int i = 0; i < 4; ++i) {
    __syncthreads();
    int lr = wm * 16 + lane15;
#pragma unroll
    for (int j = 0; j < 4; ++j) {
      shortx4 o;
#pragma unroll
      for (int r = 0; r < 4; ++r) o[r] = f2bf(acc[i][j][r]);
      *(shortx4*)&smem[lr * 264 + wn * 64 + j * 16 + quad * 4] = o;
    }
    __syncthreads();
#pragma unroll
    for (int it = 0; it < 2; ++it) {
      int t2 = tid + it * 512;
      int lr2 = t2 >> 5, c = (t2 & 31) * 8;
      short8 v = *(const short8*)&smem[lr2 * 264 + c];
      size_t rowg = (size_t)bm * 128 + (lr2 >> 4) * 64 + i * 16 + (lr2 & 15);
      short* dst = out + rowg * (size_t)N + bn * 256 + c;
      *(short8*)dst = v;
    }
  }
}

// ---------------- flash attention: block = (b, h), 512 threads, 8 waves -------------
// (R7-proven: ballot pad mask + half-width P, LDS 40960 -> 4 blocks/CU, 89 us)
__global__ __launch_bounds__(512, 4) void attn_kernel(
    const short* __restrict__ qg, const short* __restrict__ kg,
    const short* __restrict__ vtg, const int* __restrict__ ids,
    short* __restrict__ ctxg) {
  __shared__ short lds[20480];   // K[2][64][64] | V[2][64][64]@8192 | P[8][16][32]@16384
  const int tid = threadIdx.x, lane = tid & 63, w = tid >> 6;
  const int lane15 = lane & 15, quad = lane >> 4, l7 = lane15 & 7;
  const int h = blockIdx.x & 3, b = blockIdx.x >> 2;

  const int stA[2] = {w, 15 - w};
  short8 qf[2][2];
#pragma unroll
  for (int tt = 0; tt < 2; ++tt) {
    int q0 = stA[tt] * 16;
#pragma unroll
    for (int ks = 0; ks < 2; ++ks)
      qf[tt][ks] = *(const short8*)(qg + (size_t)(b * 256 + q0 + lane15) * 256 +
                                    h * 64 + ks * 32 + quad * 8);
  }

  float m_[2][4], l_[2][4];
  floatx4 o[2][4];
#pragma unroll
  for (int tt = 0; tt < 2; ++tt)
#pragma unroll
    for (int r = 0; r < 4; ++r) {
      m_[tt][r] = -1e30f; l_[tt][r] = 0.0f;
#pragma unroll
      for (int dt = 0; dt < 4; ++dt) o[tt][dt][r] = 0.0f;
    }

  // staging: thread covers row tid>>3 (0..63), 16B group (tid&7)^(row&7)
  const int srow = tid >> 3;
  const int g8 = ((tid & 7) ^ (srow & 7)) * 8;
  const short* kgp = kg + (size_t)(b * 256 + srow) * 256 + h * 64 + g8;   // + kb*64*256
  const short* vgp = vtg + (size_t)(b * 256 + h * 64 + srow) * 256 + g8;  // + kb*64
  short* pbuf = &lds[16384 + w * 512];

#define STG(kb_, ib_)                                                     \
  do {                                                                    \
    async16(kgp + (size_t)(kb_) * 64 * 256, &lds[(ib_) * 4096 + w * 512]);\
    async16(vgp + (kb_) * 64, &lds[8192 + (ib_) * 4096 + w * 512]);       \
  } while (0)

  STG(0, 0);

  for (int kb = 0; kb < 4; ++kb) {
    __syncthreads();
    if (kb < 3) STG(kb + 1, (kb + 1) & 1);
    const short* kbuf = &lds[(kb & 1) * 4096];
    const short* vbuf = &lds[8192 + (kb & 1) * 4096];
    // padding mask for this 64-key tile: bit l = (ids[b,kb*64+l] > 0)
    const unsigned long long pm = __ballot(ids[b * 256 + kb * 64 + lane] > 0);

#pragma unroll
    for (int tt = 0; tt < 2; ++tt) {
      const int st = stA[tt];
      if (st < 4 * kb) continue;                 // causally done
      const int q0 = st * 16;
      const int diag = (st >> 2) == kb;
      const int stlo = st & 3;
      floatx4 e[4];
#pragma unroll
      for (int t16 = 0; t16 < 4; ++t16) {
        if (diag && t16 > stlo) {                // fully masked sub-block
          e[t16] = (floatx4){-1e30f, -1e30f, -1e30f, -1e30f};
          continue;
        }
        floatx4 a = {0.f, 0.f, 0.f, 0.f};
#pragma unroll
        for (int ks = 0; ks < 2; ++ks) {
          short8 kf = *(const short8*)&kbuf[(t16 * 16 + lane15) * 64 +
                                            (((ks * 4 + quad) ^ l7) * 8)];
          a = __builtin_amdgcn_mfma_f32_16x16x32_bf16(qf[tt][ks], kf, a, 0, 0, 0);
        }
        float pb = ((pm >> (t16 * 16 + lane15)) & 1ull) ? 0.0f : -10000.0f;
        if (diag && t16 == stlo) {
          int kk = kb * 64 + t16 * 16 + lane15;
#pragma unroll
          for (int r = 0; r < 4; ++r)
            e[t16][r] = a[r] * 0.125f + ((kk <= q0 + quad * 4 + r) ? pb : -10000.0f);
        } else {
#pragma unroll
          for (int r = 0; r < 4; ++r) e[t16][r] = a[r] * 0.125f + pb;
        }
      }
      // online softmax over this 64-key tile; pack P rows to bf16 pairs
      unsigned pk01[4], pk23[4];
#pragma unroll
      for (int r = 0; r < 4; ++r) {
        float mx = fmaxf(fmaxf(e[0][r], e[1][r]), fmaxf(e[2][r], e[3][r]));
        mx = fmaxf(mx, __shfl_xor(mx, 1)); mx = fmaxf(mx, __shfl_xor(mx, 2));
        mx = fmaxf(mx, __shfl_xor(mx, 4)); mx = fmaxf(mx, __shfl_xor(mx, 8));
        float mn = fmaxf(m_[tt][r], mx);
        float alpha = __expf(m_[tt][r] - mn);
        m_[tt][r] = mn;
        float s = 0.0f;
#pragma unroll
        for (int t16 = 0; t16 < 4; ++t16) {
          float ev = __expf(e[t16][r] - mn);
          e[t16][r] = ev; s += ev;
        }
        s += __shfl_xor(s, 1); s += __shfl_xor(s, 2);
        s += __shfl_xor(s, 4); s += __shfl_xor(s, 8);
        l_[tt][r] = l_[tt][r] * alpha + s;
#pragma unroll
        for (int dt = 0; dt < 4; ++dt) o[tt][dt][r] *= alpha;
        pk01[r] = ((unsigned)(unsigned short)f2bf(e[0][r])) |
                  (((unsigned)(unsigned short)f2bf(e[1][r])) << 16);
        pk23[r] = ((unsigned)(unsigned short)f2bf(e[2][r])) |
                  (((unsigned)(unsigned short)f2bf(e[3][r])) << 16);
      }
      // PV in two 32-key passes through the half-width per-wave P buffer
#pragma unroll
      for (int kh = 0; kh < 2; ++kh) {
#pragma unroll
        for (int r = 0; r < 4; ++r) {
          int qloc = quad * 4 + r;
          unsigned pk = kh ? pk23[r] : pk01[r];
#pragma unroll
          for (int th = 0; th < 2; ++th) {
            int c = ((th * 2 + (lane15 >> 3)) ^ quad) & 3;
            pbuf[qloc * 32 + c * 8 + l7] = (short)(pk >> (th * 16));
          }
        }
        short8 pf = *(const short8*)&pbuf[lane15 * 32 +
                                          (((quad ^ (lane15 >> 2)) & 3) * 8)];
#pragma unroll
        for (int dt = 0; dt < 4; ++dt) {
          short8 vf = *(const short8*)&vbuf[(dt * 16 + lane15) * 64 +
                        (((kh * 4 + quad) ^ l7) * 8)];
          o[tt][dt] = __builtin_amdgcn_mfma_f32_16x16x32_bf16(pf, vf, o[tt][dt], 0, 0, 0);
        }
      }
    }
  }

  // epilogue: per wave, two passes of 16x32 through pbuf, then 16B/lane reads and
  // 64B-contiguous global stores per row.
#pragma unroll
  for (int tt = 0; tt < 2; ++tt) {
    const int q0 = stA[tt] * 16;
    float inv_[4];
#pragma unroll
    for (int r = 0; r < 4; ++r) inv_[r] = 1.0f / l_[tt][r];
#pragma unroll
    for (int p = 0; p < 2; ++p) {
#pragma unroll
      for (int r = 0; r < 4; ++r) {
        int qloc = quad * 4 + r;
#pragma unroll
        for (int dh = 0; dh < 2; ++dh) {
          int c = ((dh * 2 + (lane15 >> 3)) ^ quad) & 3;
          pbuf[qloc * 32 + c * 8 + l7] = f2bf(o[tt][p * 2 + dh][r] * inv_[r]);
        }
      }
      int row = lane >> 2, u = lane & 3;
      int lc = u ^ ((row >> 2) & 3);
      short8 v = *(const short8*)&pbuf[row * 32 + u * 8];
      *(short8*)(ctxg + (size_t)(b * 256 + q0 + row) * 256 + h * 64 + p * 32 + lc * 8) = v;
    }
  }
}

extern "C" void kernel_launch(void* const* d_in, const int* in_sizes, int n_in,
                              void* d_out, int out_size, void* d_ws, size_t ws_size,
                              hipStream_t stream) {
  const int*   ids  = (const int*)d_in[0];
  const float* item = (const float*)d_in[1];
  const float* pos  = (const float*)d_in[2];
  const float* Wq = (const float*)d_in[3];  const float* bq = (const float*)d_in[4];
  const float* Wk = (const float*)d_in[5];  const float* bk = (const float*)d_in[6];
  const float* Wv = (const float*)d_in[7];  const float* bv = (const float*)d_in[8];
  const float* Wo = (const float*)d_in[9];  const float* bo = (const float*)d_in[10];
  const float* W1 = (const float*)d_in[11]; const float* b1 = (const float*)d_in[12];
  const float* W2 = (const float*)d_in[13]; const float* b2 = (const float*)d_in[14];
  float* out = (float*)d_out;

  const size_t EL = (size_t)BQ * SQ * DQ;   // 16,777,216
  short* qb    = (short*)d_ws;
  short* kb_   = qb + EL;
  short* vt    = kb_ + EL;                  // V^T [b][d][s]
  short* ctxb  = vt + EL;
  short* gb    = qb;                        // [M,1024] spans qb..ctxb (dead at W1)
  short* xb    = ctxb + EL;
  short* hb    = xb + EL;
  short* WqkvT = hb + EL;                   // [L][3][256][256]
  short* WoT   = WqkvT + 2 * 3 * 65536;
  short* W1T   = WoT + 2 * 65536;           // [L][1024][256]
  short* W2T   = W1T + 2 * 262144;          // [L][256][1024]
  float* bqkv  = (float*)(W2T + 2 * 262144);

  const int M = BQ * SQ;                    // 65536

  wtrans_kernel<<<390, 256, 0, stream>>>(Wq, Wk, Wv, Wo, W1, W2, bq, bk, bv,
                                         WqkvT, WoT, W1T, W2T, bqkv);
  embed_kernel<<<M / 4, 256, 0, stream>>>(ids, item, pos, xb, out);

  for (int l = 0; l < 2; ++l) {
    gemm128_kernel<0, 1><<<dim3(6, M / 128), 256, 0, stream>>>(
        xb, WqkvT + (size_t)l * 3 * 65536, bqkv + l * 768, qb, vt, M, 768, 256);
    attn_kernel<<<BQ * HQ, 512, 0, stream>>>(qb, kb_, vt, ids, ctxb);
    gemm_kernel<0, 1, 1, 0, 0><<<dim3(1, M / 128), 512, 0, stream>>>(
        ctxb, WoT + (size_t)l * 65536, bo + l * 256, xb, hb, nullptr, nullptr,
        M, 256, 256);
    gemm128_kernel<1, 0><<<dim3(8, M / 128), 256, 0, stream>>>(
        hb, W1T + (size_t)l * 262144, b1 + l * 1024, gb, nullptr, M, 1024, 256);
    gemm_kernel<0, 1, 0, 1, 0><<<dim3(1, M / 128), 512, 0, stream>>>(
        gb, W2T + (size_t)l * 262144, b2 + l * 256, nullptr, xb, out, nullptr,
        M, 256, 1024);
  }
}

// Round 11
// 713.441 us; speedup vs baseline: 1.1016x; 1.0469x over previous
//
#include <hip/hip_runtime.h>
#include <math.h>

typedef __attribute__((ext_vector_type(8))) short short8;
typedef __attribute__((ext_vector_type(4))) short shortx4;
typedef __attribute__((ext_vector_type(4))) float floatx4;

#define BQ 256
#define SQ 256
#define DQ 256
#define HQ 4

__device__ __forceinline__ short f2bf(float f) {
  union { float f; unsigned u; } c; c.f = f;
  unsigned r = c.u + 0x7fffu + ((c.u >> 16) & 1u);
  return (short)(r >> 16);
}
__device__ __forceinline__ float bf2f(short s) {
  union { unsigned u; float f; } c; c.u = ((unsigned)(unsigned short)s) << 16;
  return c.f;
}
__device__ __forceinline__ float gelu_fast(float x) {
  float t = x * (0.7978845608f + 0.0356774081f * x * x);
  return x / (1.0f + __expf(-2.0f * t));
}
__device__ __forceinline__ void async16(const void* g, void* l) {
  __builtin_amdgcn_global_load_lds(
      (const __attribute__((address_space(1))) void*)g,
      (__attribute__((address_space(3))) void*)l, 16, 0, 0);
}

// ---- unified weight transpose+convert (f32 [K,N] -> bf16 [N,K]) + bias concat ------
__global__ __launch_bounds__(256) void wtrans_kernel(
    const float* __restrict__ Wq, const float* __restrict__ Wk, const float* __restrict__ Wv,
    const float* __restrict__ Wo, const float* __restrict__ W1, const float* __restrict__ W2,
    const float* __restrict__ bq, const float* __restrict__ bk, const float* __restrict__ bv,
    short* __restrict__ WqkvT, short* __restrict__ WoT, short* __restrict__ W1T,
    short* __restrict__ W2T, float* __restrict__ bqkv) {
  const int bid = blockIdx.x, tid = threadIdx.x;
  if (bid >= 384) {                       // bias concat: 6 blocks
    int i = bid - 384;                    // l*3+which
    int l = i / 3, which = i - l * 3;
    const float* src = (which == 0) ? bq : ((which == 1) ? bk : bv);
    bqkv[l * 768 + which * 256 + tid] = src[l * 256 + tid];
    return;
  }
  __shared__ float t[64][65];
  const float* src; short* dst; int K, N, tile;
  if (bid < 96)       { int l = bid / 48, r = bid % 48, which = r / 16; tile = r % 16;
    src = ((which == 0) ? Wq : (which == 1) ? Wk : Wv) + l * 65536;
    dst = WqkvT + (l * 3 + which) * 65536; K = 256; N = 256; }
  else if (bid < 128) { int i = bid - 96, l = i / 16; tile = i % 16;
    src = Wo + l * 65536; dst = WoT + l * 65536; K = 256; N = 256; }
  else if (bid < 256) { int i = bid - 128, l = i / 64; tile = i % 64;
    src = W1 + l * 262144; dst = W1T + l * 262144; K = 256; N = 1024; }
  else                { int i = bid - 256, l = i / 64; tile = i % 64;
    src = W2 + l * 262144; dst = W2T + l * 262144; K = 1024; N = 256; }
  const int ntj = N >> 6;
  const int ti = tile / ntj, tj = tile - ti * ntj;
  {
    int r = tid >> 2, c0 = (tid & 3) * 16;
    const float* sp = src + (size_t)(ti * 64 + r) * N + tj * 64 + c0;
#pragma unroll
    for (int j = 0; j < 4; ++j) {
      floatx4 v = *(const floatx4*)(sp + j * 4);
      t[r][c0 + j * 4 + 0] = v[0]; t[r][c0 + j * 4 + 1] = v[1];
      t[r][c0 + j * 4 + 2] = v[2]; t[r][c0 + j * 4 + 3] = v[3];
    }
  }
  __syncthreads();
  {
    int d = tid & 63, ch = tid >> 6;
    short8 o[2];
#pragma unroll
    for (int j = 0; j < 16; ++j) o[j >> 3][j & 7] = f2bf(t[ch * 16 + j][d]);
    short* dp = dst + (size_t)(tj * 64 + d) * K + ti * 64 + ch * 16;
    *(short8*)dp = o[0];
    *(short8*)(dp + 8) = o[1];
  }
}

// ---------------- embedding + LN; writes xb (bf16) and total (f32) ------------------
__global__ __launch_bounds__(256) void embed_kernel(const int* __restrict__ ids,
    const float* __restrict__ item, const float* __restrict__ pos,
    short* __restrict__ xb, float* __restrict__ tot) {
  const int tid = threadIdx.x, lane = tid & 63, w = tid >> 6;
  const int row = blockIdx.x * 4 + w;
  const int s = row & (SQ - 1);
  const int id = ids[row];
  floatx4 a = *(const floatx4*)(item + (size_t)id * DQ + lane * 4);
  floatx4 p = *(const floatx4*)(pos + (size_t)s * DQ + lane * 4);
  float v[4];
#pragma unroll
  for (int i = 0; i < 4; ++i) v[i] = a[i] + p[i];
  float sm = v[0] + v[1] + v[2] + v[3];
  float ss = v[0]*v[0] + v[1]*v[1] + v[2]*v[2] + v[3]*v[3];
#pragma unroll
  for (int off = 32; off; off >>= 1) { sm += __shfl_xor(sm, off); ss += __shfl_xor(ss, off); }
  float mu = sm * (1.0f / DQ);
  float var = ss * (1.0f / DQ) - mu * mu;
  float rs = rsqrtf(var + 1e-5f);
  shortx4 o; floatx4 y;
#pragma unroll
  for (int i = 0; i < 4; ++i) { y[i] = (v[i] - mu) * rs; o[i] = f2bf(y[i]); }
  *(shortx4*)(xb + (size_t)row * DQ + lane * 4) = o;
  *(floatx4*)(tot + (size_t)row * DQ + lane * 4) = y;
}

// ------------- bf16 MFMA GEMM, tile 128x128, 256 threads, 4 waves (2x2) -------------
// (R6-proven: +22 us vs 128x256 for the LN-free GEMMs)
template <int ACT, int SMODE>
__global__ __launch_bounds__(256, 4) void gemm128_kernel(
    const short* __restrict__ A, const short* __restrict__ Bt,
    const float* __restrict__ bias, short* __restrict__ out, short* __restrict__ vt,
    int M, int N, int K) {
  __shared__ short smem[16384];   // 2 x (As 4096 | Bs 4096) shorts = 32768 B
  const int tid = threadIdx.x, lane = tid & 63, w = tid >> 6;   // w in 0..3
  const int lane15 = lane & 15, quad = lane >> 4;
  const int wm = w & 1, wn = w >> 1;

  const int gx = gridDim.x;
  const int nwg = gx * gridDim.y;
  const int orig = blockIdx.y * gx + blockIdx.x;
  const int chunk = nwg >> 3;
  const int sw = (orig & 7) * chunk + (orig >> 3);
  const int bm = sw / gx, bn = sw - bm * gx;

  const int rA = lane >> 2;
  const int swzA = (rA & 3) ^ ((rA >> 2) & 3);
  const int gA = ((lane & 3) ^ swzA) * 8;
  const short* Ag  = A  + (size_t)(bm * 128 + w * 16 + rA) * K + gA;
  const short* Ag2 = Ag + (size_t)64 * K;
  const short* Bg0 = Bt + (size_t)(bn * 128 + w * 16 + rA) * K + gA;
  const short* Bg1 = Bg0 + (size_t)64 * K;
  const int qs = ((quad ^ ((lane15 & 3) ^ ((lane15 >> 2) & 3))) * 8);

  floatx4 acc[4][4] = {};
  const int nk = K >> 5;
#define GSTG2(kb_)                                                       \
  do {                                                                   \
    short* S = smem + (((kb_) & 1) * 8192);                              \
    async16(Ag  + (kb_) * 32, &S[w * 512]);                              \
    async16(Ag2 + (kb_) * 32, &S[2048 + w * 512]);                       \
    async16(Bg0 + (kb_) * 32, &S[4096 + w * 512]);                       \
    async16(Bg1 + (kb_) * 32, &S[6144 + w * 512]);                       \
  } while (0)

  GSTG2(0);
  for (int kb = 0; kb < nk; ++kb) {
    __syncthreads();                       // tile kb resident
    if (kb + 1 < nk) GSTG2(kb + 1);        // prefetch overlaps compute
    const short* Asb = smem + ((kb & 1) * 8192);
    const short* Bsb = Asb + 4096;
    short8 af[4], bfr[4];
#pragma unroll
    for (int i = 0; i < 4; ++i) {
      af[i]  = *(const short8*)&Asb[(wm * 64 + i * 16 + lane15) * 32 + qs];
      bfr[i] = *(const short8*)&Bsb[(wn * 64 + i * 16 + lane15) * 32 + qs];
    }
#pragma unroll
    for (int i = 0; i < 4; ++i)
#pragma unroll
      for (int j = 0; j < 4; ++j)
        acc[i][j] = __builtin_amdgcn_mfma_f32_16x16x32_bf16(bfr[j], af[i], acc[i][j], 0, 0, 0);
  }
#undef GSTG2

  // bias (+ gelu) pre-pass
#pragma unroll
  for (int i = 0; i < 4; ++i)
#pragma unroll
    for (int j = 0; j < 4; ++j) {
      int nloc = wn * 64 + j * 16 + quad * 4;
      floatx4 b4 = *(const floatx4*)(bias + bn * 128 + nloc);
#pragma unroll
      for (int r = 0; r < 4; ++r) {
        float z = acc[i][j][r] + b4[r];
        if (ACT) z = gelu_fast(z);
        acc[i][j][r] = z;
      }
    }

  // epilogue: stage 32x128 sub-tile per i in LDS (stride 132), then coalesced out
#pragma unroll
  for (int i = 0; i < 4; ++i) {
    __syncthreads();
    int lr = wm * 16 + lane15;             // 0..31
#pragma unroll
    for (int j = 0; j < 4; ++j) {
      shortx4 o;
#pragma unroll
      for (int r = 0; r < 4; ++r) o[r] = f2bf(acc[i][j][r]);
      *(shortx4*)&smem[lr * 132 + wn * 64 + j * 16 + quad * 4] = o;
    }
    __syncthreads();
    if (SMODE == 1 && bn >= 4) {           // V -> vt transpose path
      int d = tid & 127, grp = tid >> 7;
      short vv[16];
#pragma unroll
      for (int rr = 0; rr < 16; ++rr) vv[rr] = smem[(grp * 16 + rr) * 132 + d];
      size_t row = ((size_t)((bm >> 1) * 256 + (bn - 4) * 128 + d)) * 256 +
                   (bm & 1) * 128 + grp * 64 + i * 16;
      *(short8*)(vt + row) = *(short8*)&vv[0];
      *(short8*)(vt + row + 8) = *(short8*)&vv[8];
    } else {
#pragma unroll
      for (int it = 0; it < 2; ++it) {
        int t2 = tid + it * 256;
        int lr2 = t2 >> 4, c = (t2 & 15) * 8;
        short8 v = *(const short8*)&smem[lr2 * 132 + c];
        size_t rowg = (size_t)bm * 128 + (lr2 >> 4) * 64 + i * 16 + (lr2 & 15);
        short* dst = (SMODE == 1)
            ? out + (size_t)(bn >> 1) * M * 256 + rowg * 256 + (bn & 1) * 128 + c
            : out + rowg * (size_t)N + bn * 128 + c;
        *(short8*)dst = v;
      }
    }
  }
}

// ---------------- bf16 MFMA GEMM, tile 128x256, 512 threads, swizzled LDS -----------
// Double-buffered K-loop + XCD swizzle. Used for LN GEMMs (Wo: LN+RES, W2).
// TOT semantics: 0 = none; 1 = f32 RMW (tot += y); 2 = FINAL COMBINE
// (tot = tot + bf2f(res) + y) — W2-l1 folds x1 (still live in xb) and x2 into the
// f32 total in one pass, letting W2-l0 skip its RMW entirely (-96 MB net traffic).
// res-read (LN pass) and out-write (epilogue) may alias (xb): ordered by the
// __syncthreads between the passes; rows are block-exclusive.
template <int ACT, int LN, int RES, int TOT, int SMODE>
__global__ __launch_bounds__(512, 4) void gemm_kernel(
    const short* __restrict__ A, const short* __restrict__ Bt,
    const float* __restrict__ bias, const short* __restrict__ res,
    short* __restrict__ out, float* __restrict__ tot, short* __restrict__ vt,
    int M, int N, int K) {
  __shared__ short smem[26624];   // 2 x (As 4096 | Bs 8192) shorts = 49152 B | red @24576 (4 KB)
  float* redS  = (float*)(smem + 24576);
  float* redS2 = redS + 512;
  const int tid = threadIdx.x, lane = tid & 63, w = tid >> 6;
  const int lane15 = lane & 15, quad = lane >> 4;
  const int wm = w & 1, wn = w >> 1;

  const int gx = gridDim.x;
  const int nwg = gx * gridDim.y;
  const int orig = blockIdx.y * gx + blockIdx.x;
  const int chunk = nwg >> 3;
  const int sw = (orig & 7) * chunk + (orig >> 3);
  const int bm = sw / gx, bn = sw - bm * gx;

  const int rA = lane >> 2;
  const int swzA = (rA & 3) ^ ((rA >> 2) & 3);
  const int gA = ((lane & 3) ^ swzA) * 8;
  const short* Ag  = A  + (size_t)(bm * 128 + w * 16 + rA) * K + gA;
  const short* Bg0 = Bt + (size_t)(bn * 256 + w * 32 + rA) * K + gA;
  const short* Bg1 = Bg0 + (size_t)16 * K;
  const int qs = ((quad ^ ((lane15 & 3) ^ ((lane15 >> 2) & 3))) * 8);

  floatx4 acc[4][4] = {};
  const int nk = K >> 5;
#define GSTG(kb_)                                                        \
  do {                                                                   \
    short* As_ = smem + (((kb_) & 1) * 12288);                           \
    async16(Ag  + (kb_) * 32, &As_[w * 512]);                            \
    async16(Bg0 + (kb_) * 32, &As_[4096 + w * 1024]);                    \
    async16(Bg1 + (kb_) * 32, &As_[4096 + w * 1024 + 512]);              \
  } while (0)

  GSTG(0);
  for (int kb = 0; kb < nk; ++kb) {
    __syncthreads();                       // tile kb resident (drains vmcnt)
    if (kb + 1 < nk) GSTG(kb + 1);         // prefetch overlaps compute below
    const short* Asb = smem + ((kb & 1) * 12288);
    const short* Bsb = Asb + 4096;
    short8 af[4], bfr[4];
#pragma unroll
    for (int i = 0; i < 4; ++i) {
      af[i]  = *(const short8*)&Asb[(wm * 64 + i * 16 + lane15) * 32 + qs];
      bfr[i] = *(const short8*)&Bsb[(wn * 64 + i * 16 + lane15) * 32 + qs];
    }
#pragma unroll
    for (int i = 0; i < 4; ++i)
#pragma unroll
      for (int j = 0; j < 4; ++j)
        acc[i][j] = __builtin_amdgcn_mfma_f32_16x16x32_bf16(bfr[j], af[i], acc[i][j], 0, 0, 0);
  }
#undef GSTG

  float sum_[4], sq_[4];
#pragma unroll
  for (int i = 0; i < 4; ++i) { sum_[i] = 0.0f; sq_[i] = 0.0f; }
#pragma unroll
  for (int i = 0; i < 4; ++i) {
    size_t rowg = (size_t)bm * 128 + wm * 64 + i * 16 + lane15;
#pragma unroll
    for (int j = 0; j < 4; ++j) {
      int nloc = wn * 64 + j * 16 + quad * 4;
      floatx4 b4 = *(const floatx4*)(bias + bn * 256 + nloc);
      shortx4 r4;
      if (RES) r4 = *(const shortx4*)(res + rowg * 256 + nloc);
#pragma unroll
      for (int r = 0; r < 4; ++r) {
        float z = acc[i][j][r] + b4[r];
        if (RES) z += bf2f(r4[r]);
        if (ACT) z = gelu_fast(z);
        acc[i][j][r] = z;
        if (LN) { sum_[i] += z; sq_[i] += z * z; }
      }
    }
  }

  if (LN) {
#pragma unroll
    for (int i = 0; i < 4; ++i) {
      sum_[i] += __shfl_xor(sum_[i], 16); sum_[i] += __shfl_xor(sum_[i], 32);
      sq_[i]  += __shfl_xor(sq_[i], 16);  sq_[i]  += __shfl_xor(sq_[i], 32);
    }
    if (quad == 0) {
#pragma unroll
      for (int i = 0; i < 4; ++i) {
        int lr = wm * 64 + i * 16 + lane15;
        redS[lr * 4 + wn] = sum_[i];
        redS2[lr * 4 + wn] = sq_[i];
      }
    }
    __syncthreads();
#pragma unroll
    for (int i = 0; i < 4; ++i) {
      int lr = wm * 64 + i * 16 + lane15;
      float s = redS[lr * 4] + redS[lr * 4 + 1] + redS[lr * 4 + 2] + redS[lr * 4 + 3];
      float q = redS2[lr * 4] + redS2[lr * 4 + 1] + redS2[lr * 4 + 2] + redS2[lr * 4 + 3];
      float mu = s * (1.0f / 256.0f);
      float var = q * (1.0f / 256.0f) - mu * mu;
      float rs = rsqrtf(var + 1e-5f);
      size_t rowg = (size_t)bm * 128 + wm * 64 + i * 16 + lane15;
#pragma unroll
      for (int j = 0; j < 4; ++j) {
        int nloc = wn * 64 + j * 16 + quad * 4;
        floatx4 y;
#pragma unroll
        for (int r = 0; r < 4; ++r) y[r] = (acc[i][j][r] - mu) * rs;
        acc[i][j] = y;
        if (TOT == 1) {
          floatx4* tp = (floatx4*)(tot + rowg * 256 + nloc);
          floatx4 t = *tp;
#pragma unroll
          for (int r = 0; r < 4; ++r) t[r] += y[r];
          *tp = t;
        } else if (TOT == 2) {
          floatx4* tp = (floatx4*)(tot + rowg * 256 + nloc);
          floatx4 t = *tp;
          shortx4 x1 = *(const shortx4*)(res + rowg * 256 + nloc);
#pragma unroll
          for (int r = 0; r < 4; ++r) t[r] = t[r] + bf2f(x1[r]) + y[r];
          *tp = t;
        }
      }
    }
  }

#pragma unroll
  for (int i = 0; i < 4; ++i) {
    __syncthreads();
    int lr = wm * 16 + lane15;
#pragma unroll
    for (int j = 0; j < 4; ++j) {
      shortx4 o;
#pragma unroll
      for (int r = 0; r < 4; ++r) o[r] = f2bf(acc[i][j][r]);
      *(shortx4*)&smem[lr * 264 + wn * 64 + j * 16 + quad * 4] = o;
    }
    __syncthreads();
#pragma unroll
    for (int it = 0; it < 2; ++it) {
      int t2 = tid + it * 512;
      int lr2 = t2 >> 5, c = (t2 & 31) * 8;
      short8 v = *(const short8*)&smem[lr2 * 264 + c];
      size_t rowg = (size_t)bm * 128 + (lr2 >> 4) * 64 + i * 16 + (lr2 & 15);
      short* dst = out + rowg * (size_t)N + bn * 256 + c;
      *(short8*)dst = v;
    }
  }
}

// ---------------- flash attention: block = (b, h), 512 threads, 8 waves -------------
// (R7-proven: ballot pad mask + half-width P, LDS 40960 -> 4 blocks/CU, 89 us)
__global__ __launch_bounds__(512, 4) void attn_kernel(
    const short* __restrict__ qg, const short* __restrict__ kg,
    const short* __restrict__ vtg, const int* __restrict__ ids,
    short* __restrict__ ctxg) {
  __shared__ short lds[20480];   // K[2][64][64] | V[2][64][64]@8192 | P[8][16][32]@16384
  const int tid = threadIdx.x, lane = tid & 63, w = tid >> 6;
  const int lane15 = lane & 15, quad = lane >> 4, l7 = lane15 & 7;
  const int h = blockIdx.x & 3, b = blockIdx.x >> 2;

  const int stA[2] = {w, 15 - w};
  short8 qf[2][2];
#pragma unroll
  for (int tt = 0; tt < 2; ++tt) {
    int q0 = stA[tt] * 16;
#pragma unroll
    for (int ks = 0; ks < 2; ++ks)
      qf[tt][ks] = *(const short8*)(qg + (size_t)(b * 256 + q0 + lane15) * 256 +
                                    h * 64 + ks * 32 + quad * 8);
  }

  float m_[2][4], l_[2][4];
  floatx4 o[2][4];
#pragma unroll
  for (int tt = 0; tt < 2; ++tt)
#pragma unroll
    for (int r = 0; r < 4; ++r) {
      m_[tt][r] = -1e30f; l_[tt][r] = 0.0f;
#pragma unroll
      for (int dt = 0; dt < 4; ++dt) o[tt][dt][r] = 0.0f;
    }

  // staging: thread covers row tid>>3 (0..63), 16B group (tid&7)^(row&7)
  const int srow = tid >> 3;
  const int g8 = ((tid & 7) ^ (srow & 7)) * 8;
  const short* kgp = kg + (size_t)(b * 256 + srow) * 256 + h * 64 + g8;   // + kb*64*256
  const short* vgp = vtg + (size_t)(b * 256 + h * 64 + srow) * 256 + g8;  // + kb*64
  short* pbuf = &lds[16384 + w * 512];

#define STG(kb_, ib_)                                                     \
  do {                                                                    \
    async16(kgp + (size_t)(kb_) * 64 * 256, &lds[(ib_) * 4096 + w * 512]);\
    async16(vgp + (kb_) * 64, &lds[8192 + (ib_) * 4096 + w * 512]);       \
  } while (0)

  STG(0, 0);

  for (int kb = 0; kb < 4; ++kb) {
    __syncthreads();
    if (kb < 3) STG(kb + 1, (kb + 1) & 1);
    const short* kbuf = &lds[(kb & 1) * 4096];
    const short* vbuf = &lds[8192 + (kb & 1) * 4096];
    // padding mask for this 64-key tile: bit l = (ids[b,kb*64+l] > 0)
    const unsigned long long pm = __ballot(ids[b * 256 + kb * 64 + lane] > 0);

#pragma unroll
    for (int tt = 0; tt < 2; ++tt) {
      const int st = stA[tt];
      if (st < 4 * kb) continue;                 // causally done
      const int q0 = st * 16;
      const int diag = (st >> 2) == kb;
      const int stlo = st & 3;
      floatx4 e[4];
#pragma unroll
      for (int t16 = 0; t16 < 4; ++t16) {
        if (diag && t16 > stlo) {                // fully masked sub-block
          e[t16] = (floatx4){-1e30f, -1e30f, -1e30f, -1e30f};
          continue;
        }
        floatx4 a = {0.f, 0.f, 0.f, 0.f};
#pragma unroll
        for (int ks = 0; ks < 2; ++ks) {
          short8 kf = *(const short8*)&kbuf[(t16 * 16 + lane15) * 64 +
                                            (((ks * 4 + quad) ^ l7) * 8)];
          a = __builtin_amdgcn_mfma_f32_16x16x32_bf16(qf[tt][ks], kf, a, 0, 0, 0);
        }
        float pb = ((pm >> (t16 * 16 + lane15)) & 1ull) ? 0.0f : -10000.0f;
        if (diag && t16 == stlo) {
          int kk = kb * 64 + t16 * 16 + lane15;
#pragma unroll
          for (int r = 0; r < 4; ++r)
            e[t16][r] = a[r] * 0.125f + ((kk <= q0 + quad * 4 + r) ? pb : -10000.0f);
        } else {
#pragma unroll
          for (int r = 0; r < 4; ++r) e[t16][r] = a[r] * 0.125f + pb;
        }
      }
      // online softmax over this 64-key tile; pack P rows to bf16 pairs
      unsigned pk01[4], pk23[4];
#pragma unroll
      for (int r = 0; r < 4; ++r) {
        float mx = fmaxf(fmaxf(e[0][r], e[1][r]), fmaxf(e[2][r], e[3][r]));
        mx = fmaxf(mx, __shfl_xor(mx, 1)); mx = fmaxf(mx, __shfl_xor(mx, 2));
        mx = fmaxf(mx, __shfl_xor(mx, 4)); mx = fmaxf(mx, __shfl_xor(mx, 8));
        float mn = fmaxf(m_[tt][r], mx);
        float alpha = __expf(m_[tt][r] - mn);
        m_[tt][r] = mn;
        float s = 0.0f;
#pragma unroll
        for (int t16 = 0; t16 < 4; ++t16) {
          float ev = __expf(e[t16][r] - mn);
          e[t16][r] = ev; s += ev;
        }
        s += __shfl_xor(s, 1); s += __shfl_xor(s, 2);
        s += __shfl_xor(s, 4); s += __shfl_xor(s, 8);
        l_[tt][r] = l_[tt][r] * alpha + s;
#pragma unroll
        for (int dt = 0; dt < 4; ++dt) o[tt][dt][r] *= alpha;
        pk01[r] = ((unsigned)(unsigned short)f2bf(e[0][r])) |
                  (((unsigned)(unsigned short)f2bf(e[1][r])) << 16);
        pk23[r] = ((unsigned)(unsigned short)f2bf(e[2][r])) |
                  (((unsigned)(unsigned short)f2bf(e[3][r])) << 16);
      }
      // PV in two 32-key passes through the half-width per-wave P buffer
#pragma unroll
      for (int kh = 0; kh < 2; ++kh) {
#pragma unroll
        for (int r = 0; r < 4; ++r) {
          int qloc = quad * 4 + r;
          unsigned pk = kh ? pk23[r] : pk01[r];
#pragma unroll
          for (int th = 0; th < 2; ++th) {
            int c = ((th * 2 + (lane15 >> 3)) ^ quad) & 3;
            pbuf[qloc * 32 + c * 8 + l7] = (short)(pk >> (th * 16));
          }
        }
        short8 pf = *(const short8*)&pbuf[lane15 * 32 +
                                          (((quad ^ (lane15 >> 2)) & 3) * 8)];
#pragma unroll
        for (int dt = 0; dt < 4; ++dt) {
          short8 vf = *(const short8*)&vbuf[(dt * 16 + lane15) * 64 +
                        (((kh * 4 + quad) ^ l7) * 8)];
          o[tt][dt] = __builtin_amdgcn_mfma_f32_16x16x32_bf16(pf, vf, o[tt][dt], 0, 0, 0);
        }
      }
    }
  }

  // epilogue: per wave, two passes of 16x32 through pbuf, then 16B/lane reads and
  // 64B-contiguous global stores per row.
#pragma unroll
  for (int tt = 0; tt < 2; ++tt) {
    const int q0 = stA[tt] * 16;
    float inv_[4];
#pragma unroll
    for (int r = 0; r < 4; ++r) inv_[r] = 1.0f / l_[tt][r];
#pragma unroll
    for (int p = 0; p < 2; ++p) {
#pragma unroll
      for (int r = 0; r < 4; ++r) {
        int qloc = quad * 4 + r;
#pragma unroll
        for (int dh = 0; dh < 2; ++dh) {
          int c = ((dh * 2 + (lane15 >> 3)) ^ quad) & 3;
          pbuf[qloc * 32 + c * 8 + l7] = f2bf(o[tt][p * 2 + dh][r] * inv_[r]);
        }
      }
      int row = lane >> 2, u = lane & 3;
      int lc = u ^ ((row >> 2) & 3);
      short8 v = *(const short8*)&pbuf[row * 32 + u * 8];
      *(short8*)(ctxg + (size_t)(b * 256 + q0 + row) * 256 + h * 64 + p * 32 + lc * 8) = v;
    }
  }
}

extern "C" void kernel_launch(void* const* d_in, const int* in_sizes, int n_in,
                              void* d_out, int out_size, void* d_ws, size_t ws_size,
                              hipStream_t stream) {
  const int*   ids  = (const int*)d_in[0];
  const float* item = (const float*)d_in[1];
  const float* pos  = (const float*)d_in[2];
  const float* Wq = (const float*)d_in[3];  const float* bq = (const float*)d_in[4];
  const float* Wk = (const float*)d_in[5];  const float* bk = (const float*)d_in[6];
  const float* Wv = (const float*)d_in[7];  const float* bv = (const float*)d_in[8];
  const float* Wo = (const float*)d_in[9];  const float* bo = (const float*)d_in[10];
  const float* W1 = (const float*)d_in[11]; const float* b1 = (const float*)d_in[12];
  const float* W2 = (const float*)d_in[13]; const float* b2 = (const float*)d_in[14];
  float* out = (float*)d_out;

  const size_t EL = (size_t)BQ * SQ * DQ;   // 16,777,216
  short* qb    = (short*)d_ws;
  short* kb_   = qb + EL;
  short* vt    = kb_ + EL;                  // V^T [b][d][s]
  short* ctxb  = vt + EL;
  short* gb    = qb;                        // [M,1024] spans qb..ctxb (dead at W1)
  short* xb    = ctxb + EL;
  short* hb    = xb + EL;
  short* WqkvT = hb + EL;                   // [L][3][256][256]
  short* WoT   = WqkvT + 2 * 3 * 65536;
  short* W1T   = WoT + 2 * 65536;           // [L][1024][256]
  short* W2T   = W1T + 2 * 262144;          // [L][256][1024]
  float* bqkv  = (float*)(W2T + 2 * 262144);

  const int M = BQ * SQ;                    // 65536

  wtrans_kernel<<<390, 256, 0, stream>>>(Wq, Wk, Wv, Wo, W1, W2, bq, bk, bv,
                                         WqkvT, WoT, W1T, W2T, bqkv);
  embed_kernel<<<M / 4, 256, 0, stream>>>(ids, item, pos, xb, out);

  for (int l = 0; l < 2; ++l) {
    gemm128_kernel<0, 1><<<dim3(6, M / 128), 256, 0, stream>>>(
        xb, WqkvT + (size_t)l * 3 * 65536, bqkv + l * 768, qb, vt, M, 768, 256);
    attn_kernel<<<BQ * HQ, 512, 0, stream>>>(qb, kb_, vt, ids, ctxb);
    gemm_kernel<0, 1, 1, 0, 0><<<dim3(1, M / 128), 512, 0, stream>>>(
        ctxb, WoT + (size_t)l * 65536, bo + l * 256, xb, hb, nullptr, nullptr,
        M, 256, 256);
    gemm128_kernel<1, 0><<<dim3(8, M / 128), 256, 0, stream>>>(
        hb, W1T + (size_t)l * 262144, b1 + l * 1024, gb, nullptr, M, 1024, 256);
    if (l == 0) {
      // W2-l0: LN only, no total update (x1 stays recoverable from xb)
      gemm_kernel<0, 1, 0, 0, 0><<<dim3(1, M / 128), 512, 0, stream>>>(
          gb, W2T + (size_t)l * 262144, b2 + l * 256, nullptr, xb, nullptr, nullptr,
          M, 256, 1024);
    } else {
      // W2-l1: final combine — out = tot(x0) + bf2f(xb=x1) + y(x2); then xb <- x2
      gemm_kernel<0, 1, 0, 2, 0><<<dim3(1, M / 128), 512, 0, stream>>>(
          gb, W2T + (size_t)l * 262144, b2 + l * 256, xb, xb, out, nullptr,
          M, 256, 1024);
    }
  }
}